// Round 5
// baseline (1406.052 us; speedup 1.0000x reference)
//
#include <hip/hip_runtime.h>
#include <math.h>

#define NB 8
#define NN 4096
#define MM 2048
#define KNN_K 16
#define CIN 64
#define COUT 128
#define BN_EPS 1e-5f
#define NWORK 128
#define NTILES 512
#define BT 320  // 5 waves: 4 compute + 1 publisher (FPS) / +1 consumer (KNN)

typedef float v2f __attribute__((ext_vector_type(2)));

__device__ __forceinline__ v2f pk_add(v2f a, v2f b) {
  v2f r;
  asm("v_pk_add_f32 %0, %1, %2" : "=v"(r) : "v"(a), "v"(b));
  return r;
}
__device__ __forceinline__ v2f pk_mul(v2f a, v2f b) {
  v2f r;
  asm("v_pk_mul_f32 %0, %1, %2" : "=v"(r) : "v"(a), "v"(b));
  return r;
}

__device__ __forceinline__ double pack_key(float d, unsigned code) {
  return __longlong_as_double(
      (long long)(((unsigned long long)__float_as_uint(d) << 32) | code));
}
__device__ __forceinline__ unsigned unpack_code(double v) {
  return (unsigned)((unsigned long long)__double_as_longlong(v) &
                    0xFFFFFFFFull);
}

// numpy-exact squared distance: ((dx*dx + dy*dy) + dz*dz), no FMA contraction
__device__ __forceinline__ float sqdist_np(float dx, float dy, float dz) {
  return __fadd_rn(__fadd_rn(__fmul_rn(dx, dx), __fmul_rn(dy, dy)),
                   __fmul_rn(dz, dz));
}

// LDS-only barrier: drains lgkmcnt but NOT vmcnt, so the publisher wave's
// stores stay fire-and-forget across the block rendezvous.
__device__ __forceinline__ void bar_lds_only() {
  asm volatile("s_waitcnt lgkmcnt(0)\n\ts_barrier" ::: "memory");
}

#define DPP_MAX_LEVEL(best, ctrl, rmask)                                     \
  {                                                                          \
    const int _lo = __builtin_amdgcn_update_dpp(                             \
        __double2loint(best), __double2loint(best), (ctrl), (rmask), 0xf,    \
        false);                                                              \
    const int _hi = __builtin_amdgcn_update_dpp(                             \
        __double2hiint(best), __double2hiint(best), (ctrl), (rmask), 0xf,    \
        false);                                                              \
    best = fmax(best, __hiloint2double(_hi, _lo));                           \
  }
#define DPP_MIN_LEVEL(best, ctrl, rmask)                                     \
  {                                                                          \
    const int _lo = __builtin_amdgcn_update_dpp(                             \
        __double2loint(best), __double2loint(best), (ctrl), (rmask), 0xf,    \
        false);                                                              \
    const int _hi = __builtin_amdgcn_update_dpp(                             \
        __double2hiint(best), __double2hiint(best), (ctrl), (rmask), 0xf,    \
        false);                                                              \
    best = fmin(best, __hiloint2double(_hi, _lo));                           \
  }

__device__ __forceinline__ float gelu_exact(float v) {
  return 0.5f * v * (1.0f + erff(v * 0.70710678118654752f));
}

// ---------------------------------------------------------------------------
// Fused producer-consumer kernel, ONE BLOCK PER CU (136 blocks, 320 thr):
//   blocks 0..7   : FPS. Waves 0-3 run the R5 serial loop; per-iteration the
//                   winner lane publishes a (key,x,y,z) TUPLE to LDS, with
//                   its own candidate xyz speculatively read DURING the DPP
//                   reduce — removes the second dependent LDS round-trip
//                   (xs[last]) from the post-barrier critical path.
//                   Wave 4 = publisher: same barrier cadence, recomputes
//                   `last` from the red keys and does the pub/out_pos stores.
//   blocks 8..135 : 4 GEMM tiles each (512 = 4*128; wave 4 idles through the
//                   barriers) -> per-tile release -> stage cloud pos into LDS
//                   (SoA) -> wait gemm_done -> BN -> KNN consumer (cloud =
//                   wkr&7 == XCD, 80 waves/cloud incl. wave 4, stride 80).
// ---------------------------------------------------------------------------
__global__ __launch_bounds__(BT) void k_fused(
    const float* __restrict__ pos, const float* __restrict__ x,
    const float* __restrict__ W, const float* __restrict__ bias,
    const float* __restrict__ gamma, const float* __restrict__ beta,
    float* __restrict__ h, float* __restrict__ gsum,
    float* __restrict__ gsumsq, int* __restrict__ pub,
    int* __restrict__ gemm_done, float* __restrict__ out_x,
    float* __restrict__ out_pos, float* __restrict__ out_batch) {
  __shared__ __align__(16) char smem_raw[50176];
  const int tid = threadIdx.x;
  const int lane = tid & 63, wv = tid >> 6;

  if (blockIdx.x < NB) {
    // ------------------------- FPS -------------------------
    __builtin_amdgcn_s_setprio(3);
    float* xs = (float*)smem_raw;                   // [4096]
    float* ys = xs + NN;                            // [4096]
    float* zs = ys + NN;                            // [4096]
    double* redk = (double*)(smem_raw + 49152);     // [2][4] keys (parity)
    float* redx = (float*)(smem_raw + 49152 + 64);  // [2][4]
    float* redy = redx + 8;                         // [2][4]
    float* redz = redy + 8;                         // [2][4]
    const int b = blockIdx.x;
    const float* posc = pos + (size_t)b * NN * 3;
    for (int i = tid; i < NN; i += BT) {
      xs[i] = posc[i * 3 + 0];
      ys[i] = posc[i * 3 + 1];
      zs[i] = posc[i * 3 + 2];
    }
    __syncthreads();

    if (tid < 256) {
      // -------- compute waves 0..3: serial loop, tuple-publish ------
      v2f pxv[8], pyv[8], pzv[8];
      double key[16];
      const unsigned code_base = (unsigned)(NN - 1 - tid * 16);
#pragma unroll
      for (int u = 0; u < 8; ++u) {
        const int p = tid * 16 + 2 * u;
        pxv[u] = (v2f){xs[p], xs[p + 1]};
        pyv[u] = (v2f){ys[p], ys[p + 1]};
        pzv[u] = (v2f){zs[p], zs[p + 1]};
      }
#pragma unroll
      for (int s = 0; s < 16; ++s)
        key[s] = __hiloint2double(0x7f800000, (int)(code_base - s));

      float lx = xs[0], ly = ys[0], lz = zs[0];
      for (int m = 1; m < MM; ++m) {
        const v2f nlx = {-lx, -lx}, nly = {-ly, -ly}, nlz = {-lz, -lz};
        double b0 = 0.0, b1 = 0.0, b2 = 0.0, b3 = 0.0;
#pragma unroll
        for (int u = 0; u < 8; ++u) {
          const v2f dx = pk_add(pxv[u], nlx);
          const v2f dy = pk_add(pyv[u], nly);
          const v2f dz = pk_add(pzv[u], nlz);
          const v2f d2 =
              pk_add(pk_add(pk_mul(dx, dx), pk_mul(dy, dy)), pk_mul(dz, dz));
          const int s0 = 2 * u, s1 = 2 * u + 1;
          const float n0 =
              fminf(__int_as_float(__double2hiint(key[s0])), d2.x);
          const float n1 =
              fminf(__int_as_float(__double2hiint(key[s1])), d2.y);
          key[s0] =
              __hiloint2double(__float_as_int(n0), (int)(code_base - s0));
          key[s1] =
              __hiloint2double(__float_as_int(n1), (int)(code_base - s1));
          switch (u & 3) {
            case 0: b0 = fmax(b0, fmax(key[s0], key[s1])); break;
            case 1: b1 = fmax(b1, fmax(key[s0], key[s1])); break;
            case 2: b2 = fmax(b2, fmax(key[s0], key[s1])); break;
            default: b3 = fmax(b3, fmax(key[s0], key[s1])); break;
          }
        }
        const double loc = fmax(fmax(b0, b1), fmax(b2, b3));
        // Speculative fetch of this lane's own candidate xyz — independent
        // of the DPP chain below, so the LDS latency hides under it.
        const int lastl = (NN - 1) - (int)unpack_code(loc);
        const float sx = xs[lastl], sy = ys[lastl], sz = zs[lastl];
        double best = loc;
        DPP_MAX_LEVEL(best, 0x121, 0xf);  // row_ror:1
        DPP_MAX_LEVEL(best, 0x122, 0xf);  // row_ror:2
        DPP_MAX_LEVEL(best, 0x124, 0xf);  // row_ror:4
        DPP_MAX_LEVEL(best, 0x128, 0xf);  // row_ror:8
        DPP_MAX_LEVEL(best, 0x142, 0xa);  // row_bcast:15 -> rows 1,3
        DPP_MAX_LEVEL(best, 0x143, 0xc);  // row_bcast:31 -> rows 2,3
        // lane 63 holds the full wave max; keys are globally distinct
        // (embedded index), so exactly one lane's loc matches it.
        const int bl = __builtin_amdgcn_readlane(__double2loint(best), 63);
        const int bh = __builtin_amdgcn_readlane(__double2hiint(best), 63);
        const int par = (m & 1) * 4;
        if (__double2loint(loc) == bl && __double2hiint(loc) == bh) {
          redk[par + wv] = loc;
          redx[par + wv] = sx;
          redy[par + wv] = sy;
          redz[par + wv] = sz;
        }
        bar_lds_only();
        // One parallel LDS round: 4 tuples, then 3-level exact select.
        const double k0 = redk[par + 0], k1 = redk[par + 1];
        const double k2 = redk[par + 2], k3 = redk[par + 3];
        const float x0 = redx[par + 0], x1 = redx[par + 1];
        const float x2 = redx[par + 2], x3 = redx[par + 3];
        const float y0 = redy[par + 0], y1 = redy[par + 1];
        const float y2 = redy[par + 2], y3 = redy[par + 3];
        const float z0 = redz[par + 0], z1 = redz[par + 1];
        const float z2 = redz[par + 2], z3 = redz[par + 3];
        const double f01 = fmax(k0, k1);
        const bool s1b =
            __double_as_longlong(f01) == __double_as_longlong(k1);
        const float x01 = s1b ? x1 : x0, y01 = s1b ? y1 : y0,
                    z01 = s1b ? z1 : z0;
        const double f23 = fmax(k2, k3);
        const bool s3b =
            __double_as_longlong(f23) == __double_as_longlong(k3);
        const float x23 = s3b ? x3 : x2, y23 = s3b ? y3 : y2,
                    z23 = s3b ? z3 : z2;
        const double f = fmax(f01, f23);
        const bool sfb =
            __double_as_longlong(f) == __double_as_longlong(f23);
        lx = sfb ? x23 : x01;
        ly = sfb ? y23 : y01;
        lz = sfb ? z23 : z01;
      }
    } else {
      // -------- wave 4: publisher (same barrier cadence, off-path) --------
      double* redkp = (double*)(smem_raw + 49152);
      if (tid == 256) {
        __hip_atomic_store(&pub[b * MM], 1, __ATOMIC_RELAXED,
                           __HIP_MEMORY_SCOPE_AGENT);
        out_pos[(size_t)(b * MM) * 3 + 0] = xs[0];
        out_pos[(size_t)(b * MM) * 3 + 1] = ys[0];
        out_pos[(size_t)(b * MM) * 3 + 2] = zs[0];
      }
      for (int m = 1; m < MM; ++m) {
        bar_lds_only();  // pairs with compute waves' per-iteration barrier
        if (tid == 256) {
          const int par = (m & 1) * 4;
          const double f = fmax(fmax(redkp[par + 0], redkp[par + 1]),
                                fmax(redkp[par + 2], redkp[par + 3]));
          const int last = (NN - 1) - (int)unpack_code(f);
          const int o = b * MM + m;
          __hip_atomic_store(&pub[o], last + 1, __ATOMIC_RELAXED,
                             __HIP_MEMORY_SCOPE_AGENT);
          out_pos[(size_t)o * 3 + 0] = xs[last];
          out_pos[(size_t)o * 3 + 1] = ys[last];
          out_pos[(size_t)o * 3 + 2] = zs[last];
        }
      }
    }
    __builtin_amdgcn_s_setprio(0);
    for (int m = tid; m < MM; m += BT) out_batch[b * MM + m] = (float)b;
  } else {
    // ------------------- GEMM x4 tiles, then KNN -------------------
    const int wkr = blockIdx.x - NB;  // 0..127
    float* Wl = (float*)smem_raw;     // [64][128] 32 KB
    float* xl = Wl + CIN * COUT;      // [64][64]  16 KB
    float* bsum = (float*)(smem_raw + 49152);
    float* bsq = bsum + COUT;
    for (int i = tid; i < CIN * COUT; i += BT) Wl[i] = W[i];
#pragma unroll 1
    for (int rep = 0; rep < 4; ++rep) {
      const int t = wkr + rep * NWORK;  // 0..511, exact cover
      const int r0 = t * 64;
      for (int i = tid; i < 64 * CIN; i += BT)
        xl[i] = x[(size_t)r0 * CIN + i];
      if (tid < 256) bsum[tid] = 0.f;  // covers bsum+bsq (256 floats)
      __syncthreads();
      if (tid < 256) {
        const int cg = tid & 31, rg = tid >> 5;
        const int c = cg * 4;
        float acc[8][4];
#pragma unroll
        for (int j = 0; j < 8; ++j)
#pragma unroll
          for (int tt = 0; tt < 4; ++tt) acc[j][tt] = 0.f;
        for (int k = 0; k < CIN; ++k) {
          const float4 wk = *(const float4*)&Wl[k * COUT + c];
#pragma unroll
          for (int j = 0; j < 8; ++j) {
            const float xv = xl[(rg * 8 + j) * CIN + k];
            acc[j][0] = fmaf(xv, wk.x, acc[j][0]);
            acc[j][1] = fmaf(xv, wk.y, acc[j][1]);
            acc[j][2] = fmaf(xv, wk.z, acc[j][2]);
            acc[j][3] = fmaf(xv, wk.w, acc[j][3]);
          }
        }
        const float4 bb = *(const float4*)&bias[c];
        float s0 = 0, s1 = 0, s2 = 0, s3 = 0, q0 = 0, q1 = 0, q2 = 0, q3 = 0;
#pragma unroll
        for (int j = 0; j < 8; ++j) {
          float4 hv;
          hv.x = acc[j][0] + bb.x;
          hv.y = acc[j][1] + bb.y;
          hv.z = acc[j][2] + bb.z;
          hv.w = acc[j][3] + bb.w;
          *(float4*)&h[(size_t)(r0 + rg * 8 + j) * COUT + c] = hv;
          s0 += hv.x; s1 += hv.y; s2 += hv.z; s3 += hv.w;
          q0 += hv.x * hv.x; q1 += hv.y * hv.y;
          q2 += hv.z * hv.z; q3 += hv.w * hv.w;
        }
        atomicAdd(&bsum[c + 0], s0); atomicAdd(&bsum[c + 1], s1);
        atomicAdd(&bsum[c + 2], s2); atomicAdd(&bsum[c + 3], s3);
        atomicAdd(&bsq[c + 0], q0);  atomicAdd(&bsq[c + 1], q1);
        atomicAdd(&bsq[c + 2], q2);  atomicAdd(&bsq[c + 3], q3);
      }
      __syncthreads();
      if (tid < COUT) {
        atomicAdd(&gsum[tid], bsum[tid]);
        atomicAdd(&gsumsq[tid], bsq[tid]);
      }
      __syncthreads();  // all vmem (h stores) drained per-wave before release
      if (tid == 0) {
        __threadfence();              // wbl2: release h tile across XCDs
        atomicAdd(gemm_done, 1);
      }
    }

    // Stage this cloud's positions into LDS (SoA) while GEMM stragglers
    // finish elsewhere; overwrites Wl/xl (last reads were pre-barrier).
    const int b = wkr & 7;  // cloud == XCD (blockIdx%8 round-robin)
    float* px = (float*)smem_raw;  // [4096]
    float* py = px + NN;           // [4096]
    float* pz = py + NN;           // [4096]
    const float* posc = pos + (size_t)b * NN * 3;
    for (int i = tid; i < NN; i += BT) {
      px[i] = posc[i * 3 + 0];
      py[i] = posc[i * 3 + 1];
      pz[i] = posc[i * 3 + 2];
    }

    // Wait for every tile (136 blocks on 256 CUs -> all resident).
    if (tid == 0) {
      while (__hip_atomic_load(gemm_done, __ATOMIC_RELAXED,
                               __HIP_MEMORY_SCOPE_AGENT) < NTILES)
        __builtin_amdgcn_s_sleep(64);
    }
    __syncthreads();
    __threadfence();  // acquire: invalidate stale h lines before gathers

    float* scs = (float*)(smem_raw + 49152);  // reuse bsum region
    float* shs = scs + COUT;
    if (tid < COUT) {
      const float n = (float)(NB * NN);
      const float su = __hip_atomic_load(&gsum[tid], __ATOMIC_RELAXED,
                                         __HIP_MEMORY_SCOPE_AGENT);
      const float sq = __hip_atomic_load(&gsumsq[tid], __ATOMIC_RELAXED,
                                         __HIP_MEMORY_SCOPE_AGENT);
      const float mu = su / n;
      const float var = sq / n - mu * mu;
      const float rs = rsqrtf(var + BN_EPS);
      const float s = rs * gamma[tid];
      scs[tid] = s;
      shs[tid] = beta[tid] - mu * s;
    }
    __syncthreads();

    // ----------------------------- KNN -----------------------------
    const int widx = (wkr >> 3) * 5 + wv;  // 0..79 wave index within cloud
    const float sc0 = scs[lane], sh0 = shs[lane];
    const float sc1 = scs[lane + 64], sh1 = shs[lane + 64];
    const double DINF = __longlong_as_double(0x7FF0000000000000LL);
    const float PINF = __int_as_float(0x7f800000);
    const float* hb = h + (size_t)b * NN * COUT;
    const int* pubc = pub + b * MM;

    for (int m = widx; m < MM; m += 80) {
      // back-off spin: quick retry, then deep sleep (~2.6 us) to keep
      // coherence-point poll traffic off the fabric.
      int pv = __hip_atomic_load(&pubc[m], __ATOMIC_RELAXED,
                                 __HIP_MEMORY_SCOPE_AGENT);
      if (pv == 0) {
        __builtin_amdgcn_s_sleep(8);
        pv = __hip_atomic_load(&pubc[m], __ATOMIC_RELAXED,
                               __HIP_MEMORY_SCOPE_AGENT);
        while (pv == 0) {
          __builtin_amdgcn_s_sleep(96);
          pv = __hip_atomic_load(&pubc[m], __ATOMIC_RELAXED,
                                 __HIP_MEMORY_SCOPE_AGENT);
        }
      }
      const int qi = pv - 1;
      const float qx = px[qi], qy = py[qi], qz = pz[qi];
      double gmin[8];
#pragma unroll
      for (int g = 0; g < 8; ++g) gmin[g] = DINF;
      unsigned long long rm = 0ull;
#pragma unroll
      for (int s = 0; s < 64; ++s) {
        const int p = (s << 6) + lane;
        const float d = sqdist_np(px[p] - qx, py[p] - qy, pz[p] - qz);
        gmin[s >> 3] = fmin(gmin[s >> 3], pack_key(d, (unsigned)p));
      }
      double lmin = gmin[0];
#pragma unroll
      for (int g = 1; g < 8; ++g) lmin = fmin(lmin, gmin[g]);

      int nbr[KNN_K];
#pragma unroll
      for (int r = 0; r < KNN_K; ++r) {
        double v = lmin;
        DPP_MIN_LEVEL(v, 0x121, 0xf);  // row_ror:1
        DPP_MIN_LEVEL(v, 0x122, 0xf);  // row_ror:2
        DPP_MIN_LEVEL(v, 0x124, 0xf);  // row_ror:4
        DPP_MIN_LEVEL(v, 0x128, 0xf);  // row_ror:8
        DPP_MIN_LEVEL(v, 0x142, 0xa);  // row_bcast:15 -> rows 1,3
        DPP_MIN_LEVEL(v, 0x143, 0xc);  // row_bcast:31 -> rows 2,3
        const unsigned p =
            (unsigned)__builtin_amdgcn_readlane(__double2loint(v), 63);
        nbr[r] = (int)p;
        if (lane == (int)(p & 63)) {
          const int sr = (int)(p >> 6);  // 0..63
          rm |= (1ull << sr);
          const int g = sr >> 3;
          double nm = DINF;
#pragma unroll
          for (int j = 0; j < 8; ++j) {
            const int s2 = (g << 3) + j;
            const int pp = (s2 << 6) + lane;
            const float d =
                sqdist_np(px[pp] - qx, py[pp] - qy, pz[pp] - qz);
            double kk = pack_key(d, (unsigned)pp);
            if ((rm >> s2) & 1ull) kk = DINF;
            nm = fmin(nm, kk);
          }
#pragma unroll
          for (int gg = 0; gg < 8; ++gg)
            if (gg == g) gmin[gg] = nm;
          lmin = gmin[0];
#pragma unroll
          for (int gg = 1; gg < 8; ++gg) lmin = fmin(lmin, gmin[gg]);
        }
      }

      // min/max pool of raw h, then 2 gelu evals per channel (exact identity)
      float mx0 = -PINF, mn0 = PINF, mx1 = -PINF, mn1 = PINF;
#pragma unroll
      for (int r = 0; r < KNN_K; ++r) {
        const float* row = hb + (size_t)nbr[r] * COUT;
        const float a = row[lane], cc = row[lane + 64];
        mx0 = fmaxf(mx0, a);
        mn0 = fminf(mn0, a);
        mx1 = fmaxf(mx1, cc);
        mn1 = fminf(mn1, cc);
      }
      const int q = b * MM + m;
      const float o0 = fmaxf(gelu_exact(fmaf(mx0, sc0, sh0)),
                             gelu_exact(fmaf(mn0, sc0, sh0)));
      const float o1 = fmaxf(gelu_exact(fmaf(mx1, sc1, sh1)),
                             gelu_exact(fmaf(mn1, sc1, sh1)));
      out_x[(size_t)q * COUT + lane] = o0;
      out_x[(size_t)q * COUT + lane + 64] = o1;
    }
  }
}

// ---------------------------------------------------------------------------
extern "C" void kernel_launch(void* const* d_in, const int* in_sizes, int n_in,
                              void* d_out, int out_size, void* d_ws,
                              size_t ws_size, hipStream_t stream) {
  const float* x = (const float*)d_in[0];
  const float* pos = (const float*)d_in[1];
  // d_in[2] = batch (unused; implied by layout)
  const float* W = (const float*)d_in[3];
  const float* bias = (const float*)d_in[4];
  const float* gamma = (const float*)d_in[5];
  const float* beta = (const float*)d_in[6];

  float* out_x = (float*)d_out;                      // [B*M,128]
  float* out_pos = out_x + (size_t)NB * MM * COUT;   // [B*M,3]
  float* out_batch = out_pos + (size_t)NB * MM * 3;  // [B*M]

  char* ws = (char*)d_ws;
  float* h = (float*)ws;                     // 16 MB (raw GEMM)
  float* gsum = (float*)(ws + (size_t)16777216);
  float* gsumsq = gsum + COUT;
  int* pub = (int*)(gsumsq + COUT);          // [B*M] published fps idx + 1
  int* gemm_done = pub + NB * MM;

  // zero gsum/gsumsq (1 KB) + pub (64 KB) + gemm_done (4 B) in one shot
  (void)hipMemsetAsync(gsum, 0, 2 * COUT * sizeof(float) +
                                     NB * MM * sizeof(int) + sizeof(int),
                       stream);
  hipLaunchKernelGGL(k_fused, dim3(NB + NWORK), dim3(BT), 0, stream, pos, x,
                     W, bias, gamma, beta, h, gsum, gsumsq, pub, gemm_done,
                     out_x, out_pos, out_batch);
}

// Round 6
// 1158.946 us; speedup vs baseline: 1.2132x; 1.2132x over previous
//
#include <hip/hip_runtime.h>
#include <math.h>

#define NB 8
#define NN 4096
#define MM 2048
#define KNN_K 16
#define CIN 64
#define COUT 128
#define BN_EPS 1e-5f
#define NWORK 128
#define NTILES 512
#define BT 320  // 5 waves: 4 compute + 1 publisher (FPS) / +1 consumer (KNN)

typedef float v2f __attribute__((ext_vector_type(2)));

__device__ __forceinline__ v2f pk_add(v2f a, v2f b) {
  v2f r;
  asm("v_pk_add_f32 %0, %1, %2" : "=v"(r) : "v"(a), "v"(b));
  return r;
}
__device__ __forceinline__ v2f pk_mul(v2f a, v2f b) {
  v2f r;
  asm("v_pk_mul_f32 %0, %1, %2" : "=v"(r) : "v"(a), "v"(b));
  return r;
}

__device__ __forceinline__ double pack_key(float d, unsigned code) {
  return __longlong_as_double(
      (long long)(((unsigned long long)__float_as_uint(d) << 32) | code));
}
__device__ __forceinline__ unsigned unpack_code(double v) {
  return (unsigned)((unsigned long long)__double_as_longlong(v) &
                    0xFFFFFFFFull);
}

// numpy-exact squared distance: ((dx*dx + dy*dy) + dz*dz), no FMA contraction
__device__ __forceinline__ float sqdist_np(float dx, float dy, float dz) {
  return __fadd_rn(__fadd_rn(__fmul_rn(dx, dx), __fmul_rn(dy, dy)),
                   __fmul_rn(dz, dz));
}

// LDS-only barrier: drains lgkmcnt but NOT vmcnt, so the publisher wave's
// stores stay fire-and-forget across the block rendezvous.
__device__ __forceinline__ void bar_lds_only() {
  asm volatile("s_waitcnt lgkmcnt(0)\n\ts_barrier" ::: "memory");
}

#define DPP_MAX_LEVEL(best, ctrl, rmask)                                     \
  {                                                                          \
    const int _lo = __builtin_amdgcn_update_dpp(                             \
        __double2loint(best), __double2loint(best), (ctrl), (rmask), 0xf,    \
        false);                                                              \
    const int _hi = __builtin_amdgcn_update_dpp(                             \
        __double2hiint(best), __double2hiint(best), (ctrl), (rmask), 0xf,    \
        false);                                                              \
    best = fmax(best, __hiloint2double(_hi, _lo));                           \
  }
#define DPP_MIN_LEVEL(best, ctrl, rmask)                                     \
  {                                                                          \
    const int _lo = __builtin_amdgcn_update_dpp(                             \
        __double2loint(best), __double2loint(best), (ctrl), (rmask), 0xf,    \
        false);                                                              \
    const int _hi = __builtin_amdgcn_update_dpp(                             \
        __double2hiint(best), __double2hiint(best), (ctrl), (rmask), 0xf,    \
        false);                                                              \
    best = fmin(best, __hiloint2double(_hi, _lo));                           \
  }

__device__ __forceinline__ float gelu_exact(float v) {
  return 0.5f * v * (1.0f + erff(v * 0.70710678118654752f));
}

// ---------------------------------------------------------------------------
// Fused producer-consumer kernel, ONE BLOCK PER CU (136 blocks, 320 thr):
//   blocks 0..7   : FPS. Waves 0-3 run the byte-exact R5 serial loop with ZERO
//                   stores (publish tax removed from the barrier straggler).
//                   Wave 4 = publisher: same barrier cadence, recomputes
//                   `last` from the parity-buffered red[] and does the
//                   pub/out_pos stores — its ~80 cyc/iter hides under the
//                   compute waves' ~1200-cyc iteration.
//   blocks 8..135 : 4 GEMM tiles each (512 = 4*128; wave 4 idles through the
//                   barriers) -> per-tile release -> stage cloud pos into LDS
//                   (SoA) -> wait gemm_done -> BN -> KNN consumer (cloud =
//                   wkr&7 == XCD, 80 waves/cloud incl. wave 4, stride 80).
// NOTE (R5 post-mortem): do NOT move the coordinate fetch across the barrier
// or speculate per-lane random-index LDS reads — the iteration is one serial
// chain through the barrier; relocation adds bank-conflict rounds (+122
// ns/iter measured). This R4 structure is the measured local optimum.
// ---------------------------------------------------------------------------
__global__ __launch_bounds__(BT) void k_fused(
    const float* __restrict__ pos, const float* __restrict__ x,
    const float* __restrict__ W, const float* __restrict__ bias,
    const float* __restrict__ gamma, const float* __restrict__ beta,
    float* __restrict__ h, float* __restrict__ gsum,
    float* __restrict__ gsumsq, int* __restrict__ pub,
    int* __restrict__ gemm_done, float* __restrict__ out_x,
    float* __restrict__ out_pos, float* __restrict__ out_batch) {
  __shared__ __align__(16) char smem_raw[50176];
  const int tid = threadIdx.x;
  const int lane = tid & 63, wv = tid >> 6;

  if (blockIdx.x < NB) {
    // ------------------------- FPS -------------------------
    __builtin_amdgcn_s_setprio(3);
    float* xs = (float*)smem_raw;              // [4096]
    float* ys = xs + NN;                       // [4096]
    float* zs = ys + NN;                       // [4096]
    double* red = (double*)(smem_raw + 49152); // [2][4] parity buffered
    const int b = blockIdx.x;
    const float* posc = pos + (size_t)b * NN * 3;
    for (int i = tid; i < NN; i += BT) {
      xs[i] = posc[i * 3 + 0];
      ys[i] = posc[i * 3 + 1];
      zs[i] = posc[i * 3 + 2];
    }
    __syncthreads();

    if (tid < 256) {
      // -------- compute waves 0..3: byte-exact serial loop, no stores ------
      v2f pxv[8], pyv[8], pzv[8];
      double key[16];
      const unsigned code_base = (unsigned)(NN - 1 - tid * 16);
#pragma unroll
      for (int u = 0; u < 8; ++u) {
        const int p = tid * 16 + 2 * u;
        pxv[u] = (v2f){xs[p], xs[p + 1]};
        pyv[u] = (v2f){ys[p], ys[p + 1]};
        pzv[u] = (v2f){zs[p], zs[p + 1]};
      }
#pragma unroll
      for (int s = 0; s < 16; ++s)
        key[s] = __hiloint2double(0x7f800000, (int)(code_base - s));

      int last = 0;
      float lx = xs[0], ly = ys[0], lz = zs[0];
      for (int m = 1; m < MM; ++m) {
        const v2f nlx = {-lx, -lx}, nly = {-ly, -ly}, nlz = {-lz, -lz};
        double b0 = 0.0, b1 = 0.0, b2 = 0.0, b3 = 0.0;
#pragma unroll
        for (int u = 0; u < 8; ++u) {
          const v2f dx = pk_add(pxv[u], nlx);
          const v2f dy = pk_add(pyv[u], nly);
          const v2f dz = pk_add(pzv[u], nlz);
          const v2f d2 =
              pk_add(pk_add(pk_mul(dx, dx), pk_mul(dy, dy)), pk_mul(dz, dz));
          const int s0 = 2 * u, s1 = 2 * u + 1;
          const float n0 =
              fminf(__int_as_float(__double2hiint(key[s0])), d2.x);
          const float n1 =
              fminf(__int_as_float(__double2hiint(key[s1])), d2.y);
          key[s0] =
              __hiloint2double(__float_as_int(n0), (int)(code_base - s0));
          key[s1] =
              __hiloint2double(__float_as_int(n1), (int)(code_base - s1));
          switch (u & 3) {
            case 0: b0 = fmax(b0, fmax(key[s0], key[s1])); break;
            case 1: b1 = fmax(b1, fmax(key[s0], key[s1])); break;
            case 2: b2 = fmax(b2, fmax(key[s0], key[s1])); break;
            default: b3 = fmax(b3, fmax(key[s0], key[s1])); break;
          }
        }
        double best = fmax(fmax(b0, b1), fmax(b2, b3));
        DPP_MAX_LEVEL(best, 0x121, 0xf);  // row_ror:1
        DPP_MAX_LEVEL(best, 0x122, 0xf);  // row_ror:2
        DPP_MAX_LEVEL(best, 0x124, 0xf);  // row_ror:4
        DPP_MAX_LEVEL(best, 0x128, 0xf);  // row_ror:8
        DPP_MAX_LEVEL(best, 0x142, 0xa);  // row_bcast:15 -> rows 1,3
        DPP_MAX_LEVEL(best, 0x143, 0xc);  // row_bcast:31 -> rows 2,3
        const int par = (m & 1) * 4;
        if (lane == 63) red[par + wv] = best;
        bar_lds_only();
        const double f = fmax(fmax(red[par + 0], red[par + 1]),
                              fmax(red[par + 2], red[par + 3]));
        last = (NN - 1) - (int)unpack_code(f);
        lx = xs[last];
        ly = ys[last];
        lz = zs[last];
      }
      (void)last;
    } else {
      // -------- wave 4: publisher (same barrier cadence, off-path) --------
      if (tid == 256) {
        __hip_atomic_store(&pub[b * MM], 1, __ATOMIC_RELAXED,
                           __HIP_MEMORY_SCOPE_AGENT);
        out_pos[(size_t)(b * MM) * 3 + 0] = xs[0];
        out_pos[(size_t)(b * MM) * 3 + 1] = ys[0];
        out_pos[(size_t)(b * MM) * 3 + 2] = zs[0];
      }
      for (int m = 1; m < MM; ++m) {
        bar_lds_only();  // pairs with compute waves' per-iteration barrier
        if (tid == 256) {
          const int par = (m & 1) * 4;
          const double f = fmax(fmax(red[par + 0], red[par + 1]),
                                fmax(red[par + 2], red[par + 3]));
          const int last = (NN - 1) - (int)unpack_code(f);
          const int o = b * MM + m;
          __hip_atomic_store(&pub[o], last + 1, __ATOMIC_RELAXED,
                             __HIP_MEMORY_SCOPE_AGENT);
          out_pos[(size_t)o * 3 + 0] = xs[last];
          out_pos[(size_t)o * 3 + 1] = ys[last];
          out_pos[(size_t)o * 3 + 2] = zs[last];
        }
      }
    }
    __builtin_amdgcn_s_setprio(0);
    for (int m = tid; m < MM; m += BT) out_batch[b * MM + m] = (float)b;
  } else {
    // ------------------- GEMM x4 tiles, then KNN -------------------
    const int wkr = blockIdx.x - NB;  // 0..127
    float* Wl = (float*)smem_raw;     // [64][128] 32 KB
    float* xl = Wl + CIN * COUT;      // [64][64]  16 KB
    float* bsum = (float*)(smem_raw + 49152);
    float* bsq = bsum + COUT;
    for (int i = tid; i < CIN * COUT; i += BT) Wl[i] = W[i];
#pragma unroll 1
    for (int rep = 0; rep < 4; ++rep) {
      const int t = wkr + rep * NWORK;  // 0..511, exact cover
      const int r0 = t * 64;
      for (int i = tid; i < 64 * CIN; i += BT)
        xl[i] = x[(size_t)r0 * CIN + i];
      if (tid < 256) bsum[tid] = 0.f;  // covers bsum+bsq (256 floats)
      __syncthreads();
      if (tid < 256) {
        const int cg = tid & 31, rg = tid >> 5;
        const int c = cg * 4;
        float acc[8][4];
#pragma unroll
        for (int j = 0; j < 8; ++j)
#pragma unroll
          for (int tt = 0; tt < 4; ++tt) acc[j][tt] = 0.f;
        for (int k = 0; k < CIN; ++k) {
          const float4 wk = *(const float4*)&Wl[k * COUT + c];
#pragma unroll
          for (int j = 0; j < 8; ++j) {
            const float xv = xl[(rg * 8 + j) * CIN + k];
            acc[j][0] = fmaf(xv, wk.x, acc[j][0]);
            acc[j][1] = fmaf(xv, wk.y, acc[j][1]);
            acc[j][2] = fmaf(xv, wk.z, acc[j][2]);
            acc[j][3] = fmaf(xv, wk.w, acc[j][3]);
          }
        }
        const float4 bb = *(const float4*)&bias[c];
        float s0 = 0, s1 = 0, s2 = 0, s3 = 0, q0 = 0, q1 = 0, q2 = 0, q3 = 0;
#pragma unroll
        for (int j = 0; j < 8; ++j) {
          float4 hv;
          hv.x = acc[j][0] + bb.x;
          hv.y = acc[j][1] + bb.y;
          hv.z = acc[j][2] + bb.z;
          hv.w = acc[j][3] + bb.w;
          *(float4*)&h[(size_t)(r0 + rg * 8 + j) * COUT + c] = hv;
          s0 += hv.x; s1 += hv.y; s2 += hv.z; s3 += hv.w;
          q0 += hv.x * hv.x; q1 += hv.y * hv.y;
          q2 += hv.z * hv.z; q3 += hv.w * hv.w;
        }
        atomicAdd(&bsum[c + 0], s0); atomicAdd(&bsum[c + 1], s1);
        atomicAdd(&bsum[c + 2], s2); atomicAdd(&bsum[c + 3], s3);
        atomicAdd(&bsq[c + 0], q0);  atomicAdd(&bsq[c + 1], q1);
        atomicAdd(&bsq[c + 2], q2);  atomicAdd(&bsq[c + 3], q3);
      }
      __syncthreads();
      if (tid < COUT) {
        atomicAdd(&gsum[tid], bsum[tid]);
        atomicAdd(&gsumsq[tid], bsq[tid]);
      }
      __syncthreads();  // all vmem (h stores) drained per-wave before release
      if (tid == 0) {
        __threadfence();              // wbl2: release h tile across XCDs
        atomicAdd(gemm_done, 1);
      }
    }

    // Stage this cloud's positions into LDS (SoA) while GEMM stragglers
    // finish elsewhere; overwrites Wl/xl (last reads were pre-barrier).
    const int b = wkr & 7;  // cloud == XCD (blockIdx%8 round-robin)
    float* px = (float*)smem_raw;  // [4096]
    float* py = px + NN;           // [4096]
    float* pz = py + NN;           // [4096]
    const float* posc = pos + (size_t)b * NN * 3;
    for (int i = tid; i < NN; i += BT) {
      px[i] = posc[i * 3 + 0];
      py[i] = posc[i * 3 + 1];
      pz[i] = posc[i * 3 + 2];
    }

    // Wait for every tile (136 blocks on 256 CUs -> all resident).
    if (tid == 0) {
      while (__hip_atomic_load(gemm_done, __ATOMIC_RELAXED,
                               __HIP_MEMORY_SCOPE_AGENT) < NTILES)
        __builtin_amdgcn_s_sleep(64);
    }
    __syncthreads();
    __threadfence();  // acquire: invalidate stale h lines before gathers

    float* scs = (float*)(smem_raw + 49152);  // reuse bsum region
    float* shs = scs + COUT;
    if (tid < COUT) {
      const float n = (float)(NB * NN);
      const float su = __hip_atomic_load(&gsum[tid], __ATOMIC_RELAXED,
                                         __HIP_MEMORY_SCOPE_AGENT);
      const float sq = __hip_atomic_load(&gsumsq[tid], __ATOMIC_RELAXED,
                                         __HIP_MEMORY_SCOPE_AGENT);
      const float mu = su / n;
      const float var = sq / n - mu * mu;
      const float rs = rsqrtf(var + BN_EPS);
      const float s = rs * gamma[tid];
      scs[tid] = s;
      shs[tid] = beta[tid] - mu * s;
    }
    __syncthreads();

    // ----------------------------- KNN -----------------------------
    const int widx = (wkr >> 3) * 5 + wv;  // 0..79 wave index within cloud
    const float sc0 = scs[lane], sh0 = shs[lane];
    const float sc1 = scs[lane + 64], sh1 = shs[lane + 64];
    const double DINF = __longlong_as_double(0x7FF0000000000000LL);
    const float PINF = __int_as_float(0x7f800000);
    const float* hb = h + (size_t)b * NN * COUT;
    const int* pubc = pub + b * MM;

    for (int m = widx; m < MM; m += 80) {
      // back-off spin: quick retry, then deep sleep (~2.6 us) to keep
      // coherence-point poll traffic off the fabric.
      int pv = __hip_atomic_load(&pubc[m], __ATOMIC_RELAXED,
                                 __HIP_MEMORY_SCOPE_AGENT);
      if (pv == 0) {
        __builtin_amdgcn_s_sleep(8);
        pv = __hip_atomic_load(&pubc[m], __ATOMIC_RELAXED,
                               __HIP_MEMORY_SCOPE_AGENT);
        while (pv == 0) {
          __builtin_amdgcn_s_sleep(96);
          pv = __hip_atomic_load(&pubc[m], __ATOMIC_RELAXED,
                                 __HIP_MEMORY_SCOPE_AGENT);
        }
      }
      const int qi = pv - 1;
      const float qx = px[qi], qy = py[qi], qz = pz[qi];
      double gmin[8];
#pragma unroll
      for (int g = 0; g < 8; ++g) gmin[g] = DINF;
      unsigned long long rm = 0ull;
#pragma unroll
      for (int s = 0; s < 64; ++s) {
        const int p = (s << 6) + lane;
        const float d = sqdist_np(px[p] - qx, py[p] - qy, pz[p] - qz);
        gmin[s >> 3] = fmin(gmin[s >> 3], pack_key(d, (unsigned)p));
      }
      double lmin = gmin[0];
#pragma unroll
      for (int g = 1; g < 8; ++g) lmin = fmin(lmin, gmin[g]);

      int nbr[KNN_K];
#pragma unroll
      for (int r = 0; r < KNN_K; ++r) {
        double v = lmin;
        DPP_MIN_LEVEL(v, 0x121, 0xf);  // row_ror:1
        DPP_MIN_LEVEL(v, 0x122, 0xf);  // row_ror:2
        DPP_MIN_LEVEL(v, 0x124, 0xf);  // row_ror:4
        DPP_MIN_LEVEL(v, 0x128, 0xf);  // row_ror:8
        DPP_MIN_LEVEL(v, 0x142, 0xa);  // row_bcast:15 -> rows 1,3
        DPP_MIN_LEVEL(v, 0x143, 0xc);  // row_bcast:31 -> rows 2,3
        const unsigned p =
            (unsigned)__builtin_amdgcn_readlane(__double2loint(v), 63);
        nbr[r] = (int)p;
        if (lane == (int)(p & 63)) {
          const int sr = (int)(p >> 6);  // 0..63
          rm |= (1ull << sr);
          const int g = sr >> 3;
          double nm = DINF;
#pragma unroll
          for (int j = 0; j < 8; ++j) {
            const int s2 = (g << 3) + j;
            const int pp = (s2 << 6) + lane;
            const float d =
                sqdist_np(px[pp] - qx, py[pp] - qy, pz[pp] - qz);
            double kk = pack_key(d, (unsigned)pp);
            if ((rm >> s2) & 1ull) kk = DINF;
            nm = fmin(nm, kk);
          }
#pragma unroll
          for (int gg = 0; gg < 8; ++gg)
            if (gg == g) gmin[gg] = nm;
          lmin = gmin[0];
#pragma unroll
          for (int gg = 1; gg < 8; ++gg) lmin = fmin(lmin, gmin[gg]);
        }
      }

      // min/max pool of raw h, then 2 gelu evals per channel (exact identity)
      float mx0 = -PINF, mn0 = PINF, mx1 = -PINF, mn1 = PINF;
#pragma unroll
      for (int r = 0; r < KNN_K; ++r) {
        const float* row = hb + (size_t)nbr[r] * COUT;
        const float a = row[lane], cc = row[lane + 64];
        mx0 = fmaxf(mx0, a);
        mn0 = fminf(mn0, a);
        mx1 = fmaxf(mx1, cc);
        mn1 = fminf(mn1, cc);
      }
      const int q = b * MM + m;
      const float o0 = fmaxf(gelu_exact(fmaf(mx0, sc0, sh0)),
                             gelu_exact(fmaf(mn0, sc0, sh0)));
      const float o1 = fmaxf(gelu_exact(fmaf(mx1, sc1, sh1)),
                             gelu_exact(fmaf(mn1, sc1, sh1)));
      out_x[(size_t)q * COUT + lane] = o0;
      out_x[(size_t)q * COUT + lane + 64] = o1;
    }
  }
}

// ---------------------------------------------------------------------------
extern "C" void kernel_launch(void* const* d_in, const int* in_sizes, int n_in,
                              void* d_out, int out_size, void* d_ws,
                              size_t ws_size, hipStream_t stream) {
  const float* x = (const float*)d_in[0];
  const float* pos = (const float*)d_in[1];
  // d_in[2] = batch (unused; implied by layout)
  const float* W = (const float*)d_in[3];
  const float* bias = (const float*)d_in[4];
  const float* gamma = (const float*)d_in[5];
  const float* beta = (const float*)d_in[6];

  float* out_x = (float*)d_out;                      // [B*M,128]
  float* out_pos = out_x + (size_t)NB * MM * COUT;   // [B*M,3]
  float* out_batch = out_pos + (size_t)NB * MM * 3;  // [B*M]

  char* ws = (char*)d_ws;
  float* h = (float*)ws;                     // 16 MB (raw GEMM)
  float* gsum = (float*)(ws + (size_t)16777216);
  float* gsumsq = gsum + COUT;
  int* pub = (int*)(gsumsq + COUT);          // [B*M] published fps idx + 1
  int* gemm_done = pub + NB * MM;

  // zero gsum/gsumsq (1 KB) + pub (64 KB) + gemm_done (4 B) in one shot
  (void)hipMemsetAsync(gsum, 0, 2 * COUT * sizeof(float) +
                                     NB * MM * sizeof(int) + sizeof(int),
                       stream);
  hipLaunchKernelGGL(k_fused, dim3(NB + NWORK), dim3(BT), 0, stream, pos, x,
                     W, bias, gamma, beta, h, gsum, gsumsq, pub, gemm_done,
                     out_x, out_pos, out_batch);
}